// Round 8
// baseline (2007.476 us; speedup 1.0000x reference)
//
#include <hip/hip_runtime.h>
#include <cstdint>
#include <cstddef>

#define BB   16
#define NN   4096
#define CINN 64
#define KKK  64
#define HIDD 128
#define SSS  1024
#define MAXC 512
#define NCH  8
#define CHS  (SSS / NCH)   // 128 FPS steps per chunk

typedef __attribute__((ext_vector_type(8))) short short8;
typedef __attribute__((ext_vector_type(4))) float f32x4;
typedef unsigned long long u64;

// Exact f32 squared distance, numpy-style: ((dx*dx + dy*dy) + dz*dz), no FMA contraction.
// MUST stay bit-identical (absmax 0.0 in round 1 proved selection equivalence).
__device__ __forceinline__ float d2_exact(float ax, float ay, float az,
                                          float bx, float by, float bz) {
  float dx = __fsub_rn(ax, bx);
  float dy = __fsub_rn(ay, by);
  float dz = __fsub_rn(az, bz);
  return __fadd_rn(__fadd_rn(__fmul_rn(dx, dx), __fmul_rn(dy, dy)), __fmul_rn(dz, dz));
}

// f32 -> bf16 round-to-nearest-even (no NaN inputs here)
__device__ __forceinline__ unsigned short f2bf(float f) {
  unsigned u = __float_as_uint(f);
  return (unsigned short)((u + 0x7fffu + ((u >> 16) & 1u)) >> 16);
}

// ---------------- FPS role: chunked, 256 thr, 16 pts/thread, u64-DPP argmax ----------------
__device__ __forceinline__ void fps_role(int chunk, int bid, int tid,
                                         const float* __restrict__ pos,
                                         int* __restrict__ fps_idx,
                                         float* __restrict__ md_ws,
                                         int* __restrict__ last_ws,
                                         float* __restrict__ pos_out,
                                         float* __restrict__ batch_out,
                                         char* smem) {
  float* px = (float*)smem;
  float* py = px + NN;
  float* pz = py + NN;
  u64* slots = (u64*)(pz + NN);  // [2][4] parity-double-buffered wave leaders
  const float* pb = pos + (size_t)bid * NN * 3;
  for (int i = tid; i < NN; i += 256) {
    px[i] = pb[3 * i + 0];
    py[i] = pb[3 * i + 1];
    pz[i] = pb[3 * i + 2];
  }
  if (chunk == 0) {
    #pragma unroll
    for (int kk = 0; kk < 4; ++kk)
      batch_out[bid * SSS + kk * 256 + tid] = (float)bid;
  }
  __syncthreads();

  float qx[16], qy[16], qz[16], md[16];
  #pragma unroll
  for (int j = 0; j < 16; ++j) {
    const int i = j * 256 + tid;
    qx[j] = px[i]; qy[j] = py[i]; qz[j] = pz[i];
    asm volatile("" : "+v"(qx[j]), "+v"(qy[j]), "+v"(qz[j]));
  }
  int last, tb;
  const int te = (chunk + 1) * CHS;
  if (chunk == 0) {
    #pragma unroll
    for (int j = 0; j < 16; ++j) md[j] = __builtin_inff();
    last = 0; tb = 1;
    if (tid == 0) {
      fps_idx[bid * SSS] = 0;
      pos_out[(size_t)bid * SSS * 3 + 0] = px[0];
      pos_out[(size_t)bid * SSS * 3 + 1] = py[0];
      pos_out[(size_t)bid * SSS * 3 + 2] = pz[0];
    }
  } else {
    #pragma unroll
    for (int j = 0; j < 16; ++j) md[j] = md_ws[bid * 4096 + j * 256 + tid];
    last = last_ws[bid]; tb = chunk * CHS;
  }

  for (int t = tb; t < te; ++t) {
    const float lx = px[last], ly = py[last], lz = pz[last];  // LDS broadcast
    float bv = -1.f;
    int bj = 0;
    #pragma unroll
    for (int j = 0; j < 16; ++j) {
      const float d = d2_exact(qx[j], qy[j], qz[j], lx, ly, lz);
      md[j] = fminf(md[j], d);
      if (md[j] > bv) { bv = md[j]; bj = j; }  // strict > : lowest j among ties
    }
    // key = (valbits<<32) | ~idx : u64 max == (max val, lowest idx) == jnp.argmax
    unsigned klo = ~(unsigned)(bj * 256 + tid);
    unsigned khi = __float_as_uint(bv);
    // DPP wavefront max-reduce to lane 63 (round-7 proven; old=0 + bound_ctrl => invalid
    // lanes contribute 0, identity for unsigned max).
#define FPS_DPP_STAGE(CTRL, RMASK)                                                            \
    {                                                                                          \
      unsigned slo = (unsigned)__builtin_amdgcn_update_dpp(0, (int)klo, CTRL, RMASK, 0xf, true); \
      unsigned shi = (unsigned)__builtin_amdgcn_update_dpp(0, (int)khi, CTRL, RMASK, 0xf, true); \
      if ((((u64)shi << 32) | slo) > (((u64)khi << 32) | klo)) { khi = shi; klo = slo; }       \
    }
    FPS_DPP_STAGE(0x111, 0xf)  // row_shr:1
    FPS_DPP_STAGE(0x112, 0xf)  // row_shr:2
    FPS_DPP_STAGE(0x114, 0xf)  // row_shr:4
    FPS_DPP_STAGE(0x118, 0xf)  // row_shr:8
    FPS_DPP_STAGE(0x142, 0xa)  // row_bcast:15
    FPS_DPP_STAGE(0x143, 0xc)  // row_bcast:31 -> lane63 = wave max
#undef FPS_DPP_STAGE
    u64* sl = slots + (t & 1) * 4;
    if ((tid & 63) == 63) sl[tid >> 6] = ((u64)khi << 32) | klo;
    __syncthreads();  // single barrier/step
    u64 mm = sl[0];
    #pragma unroll
    for (int w = 1; w < 4; ++w) mm = sl[w] > mm ? sl[w] : mm;
    last = (int)(~(unsigned)(mm & 0xffffffffull));
    if (tid == 0) {
      fps_idx[bid * SSS + t] = last;
      pos_out[((size_t)bid * SSS + t) * 3 + 0] = px[last];
      pos_out[((size_t)bid * SSS + t) * 3 + 1] = py[last];
      pos_out[((size_t)bid * SSS + t) * 3 + 2] = pz[last];
    }
  }
  if (chunk != NCH - 1) {
    #pragma unroll
    for (int j = 0; j < 16; ++j) md_ws[bid * 4096 + j * 256 + tid] = md[j];
    if (tid == 0) last_ws[bid] = last;
  }
}

// ---------------- y1 role: y1 = x @ W1[0:64,:], 8 points/block (round-3 proven) ----------------
__device__ __forceinline__ void y1_role(int i, int tid,
                                        const float* __restrict__ x,
                                        const float* __restrict__ W1,
                                        float* __restrict__ y1,
                                        char* smem) {
  float* sW = (float*)smem;             // [64][128] 32KB
  float* sx = (float*)(smem + 32768);   // [8][64] 2KB
  const int p0 = i * 8;
  for (int e = tid; e < CINN * HIDD; e += 256) sW[e] = W1[e];
  for (int e = tid; e < 8 * CINN; e += 256) sx[e] = x[(size_t)p0 * CINN + e];
  __syncthreads();
  const int h = tid & 127;
  const int pg = (tid >> 7) * 4;
  float a0 = 0.f, a1 = 0.f, a2 = 0.f, a3 = 0.f;
  for (int c = 0; c < CINN; ++c) {
    const float w = sW[c * HIDD + h];
    a0 = fmaf(sx[(pg + 0) * CINN + c], w, a0);
    a1 = fmaf(sx[(pg + 1) * CINN + c], w, a1);
    a2 = fmaf(sx[(pg + 2) * CINN + c], w, a2);
    a3 = fmaf(sx[(pg + 3) * CINN + c], w, a3);
  }
  y1[(size_t)(p0 + pg + 0) * HIDD + h] = a0;
  y1[(size_t)(p0 + pg + 1) * HIDD + h] = a1;
  y1[(size_t)(p0 + pg + 2) * HIDD + h] = a2;
  y1[(size_t)(p0 + pg + 3) * HIDD + h] = a3;
}

// ---------------- bq role: ball query for one center (round-3 proven body) ----------------
__device__ __forceinline__ void bq_role(int cc, int i, int tid,
                                        const float* __restrict__ pos,
                                        const int* __restrict__ fps_idx,
                                        int* __restrict__ nbr,
                                        int* __restrict__ cnt,
                                        char* smem) {
  const int b = i >> 7;
  const int g = b * 1024 + cc * CHS + (i & 127);
  float* s_cd = (float*)smem;              // [512]
  int* s_ci = (int*)(smem + 2048);         // [512]
  int* s_c = (int*)(smem + 4096);          // [0]=cnt [1]=scnt
  if (tid == 0) { s_c[0] = 0; s_c[1] = 0; }
  const float* pb = pos + (size_t)b * NN * 3;
  const int cpt = fps_idx[g];
  const float cx = pb[cpt * 3 + 0], cy = pb[cpt * 3 + 1], cz = pb[cpt * 3 + 2];
  __syncthreads();
  for (int i2 = tid; i2 < NN; i2 += 256) {
    const float d2 = d2_exact(pb[i2 * 3 + 0], pb[i2 * 3 + 1], pb[i2 * 3 + 2], cx, cy, cz);
    if (d2 <= 0.04f) {
      const int slot = atomicAdd(&s_c[0], 1);
      if (slot < MAXC) { s_cd[slot] = d2; s_ci[slot] = i2; }
    }
  }
  __syncthreads();
  const int C = min(s_c[0], MAXC);
  // exact lex-rank (d2, idx) == lax.top_k tie-break; order-independent
  for (int j = tid; j < C; j += 256) {
    const float dj = s_cd[j];
    const int ij = s_ci[j];
    int rank = 0;
    for (int m = 0; m < C; ++m) {
      const float dm = s_cd[m];
      const int im = s_ci[m];
      rank += (dm < dj || (dm == dj && im < ij)) ? 1 : 0;
    }
    if (rank < KKK) nbr[(size_t)g * KKK + atomicAdd(&s_c[1], 1)] = ij;
  }
  __syncthreads();
  if (tid == 0) cnt[g] = s_c[1];
}

// ---------------- mlp role: gather + layer1-corr + bf16 MFMA layer2 + masked max ----------------
__device__ __forceinline__ void mlp_role(int cc, int i, int tid,
                                         const float* __restrict__ pos,
                                         const float* __restrict__ y1,
                                         const float* __restrict__ W1,
                                         const float* __restrict__ b1,
                                         const unsigned short* __restrict__ W2t,
                                         const float* __restrict__ b2,
                                         const int* __restrict__ fps_idx,
                                         const int* __restrict__ nbr,
                                         const int* __restrict__ cnt,
                                         float* __restrict__ out,
                                         char* smem) {
  const int b = i >> 6;
  const int g0 = b * 1024 + cc * CHS + (i & 63) * 2;
  float* s_ctr = (float*)(smem + 65536);  // [2][3]
  int* s_M = (int*)(smem + 65568);        // [2]

  // stage W2t (128 rows x 256B, 16 uint4/row) with 16B XOR swizzle (T2)
  for (int c = tid; c < 2048; c += 256) {
    const int row = c >> 4;
    const int col = (c & 15) << 4;
    const uint4 v = ((const uint4*)W2t)[c];
    *(uint4*)(smem + row * 256 + (col ^ ((row & 7) << 4))) = v;
  }
  if (tid < 2) {
    s_M[tid] = min(cnt[g0 + tid], KKK);
    const int cp = fps_idx[g0 + tid];
    s_ctr[tid * 3 + 0] = pos[((size_t)b * NN + cp) * 3 + 0];
    s_ctr[tid * 3 + 1] = pos[((size_t)b * NN + cp) * 3 + 1];
    s_ctr[tid * 3 + 2] = pos[((size_t)b * NN + cp) * 3 + 2];
  }
  __syncthreads();

  const int wv = tid >> 6, ln = tid & 63;
  const float2 b1v = *(const float2*)(b1 + ln * 2);
  const float2 wav = *(const float2*)(W1 + 64 * HIDD + ln * 2);
  const float2 wbv = *(const float2*)(W1 + 65 * HIDD + ln * 2);
  const float2 wcv = *(const float2*)(W1 + 66 * HIDD + ln * 2);
  char* Hb = smem + 32768;
  for (int r = wv * 32; r < wv * 32 + 32; ++r) {   // row r: center r>>6, neighbor k=r&63
    const int ci = r >> 6, k = r & 63;
    unsigned val = 0u;
    if (k < s_M[ci]) {
      const int p = nbr[(size_t)(g0 + ci) * KKK + k];
      const float rx = pos[((size_t)b * NN + p) * 3 + 0] - s_ctr[ci * 3 + 0];
      const float ry = pos[((size_t)b * NN + p) * 3 + 1] - s_ctr[ci * 3 + 1];
      const float rz = pos[((size_t)b * NN + p) * 3 + 2] - s_ctr[ci * 3 + 2];
      const float2 yv = *(const float2*)(y1 + ((size_t)(b * NN + p)) * HIDD + ln * 2);
      float v0 = fmaxf(yv.x + b1v.x + rx * wav.x + ry * wbv.x + rz * wcv.x, 0.f);
      float v1 = fmaxf(yv.y + b1v.y + rx * wav.y + ry * wbv.y + rz * wcv.y, 0.f);
      val = (unsigned)f2bf(v0) | ((unsigned)f2bf(v1) << 16);
    }
    *(unsigned*)(Hb + r * 256 + ((ln * 4) ^ ((r & 7) << 4))) = val;
  }
  __syncthreads();

  // MFMA: wave (mw=center, nw=col-half); 4x4 16x16 tiles; K=128 in 4 steps of 32
  const int mw = wv >> 1, nw = wv & 1;
  const int lr = ln & 15, lg = ln >> 4;
  f32x4 zero = {0.f, 0.f, 0.f, 0.f};
  f32x4 acc[4][4];
  #pragma unroll
  for (int mi = 0; mi < 4; ++mi)
    #pragma unroll
    for (int ni = 0; ni < 4; ++ni) acc[mi][ni] = zero;

  #pragma unroll
  for (int ks = 0; ks < 4; ++ks) {
    short8 af[4], bf_[4];
    #pragma unroll
    for (int mi = 0; mi < 4; ++mi) {
      const int row = mw * 64 + mi * 16 + lr;
      af[mi] = *(const short8*)(Hb + row * 256 + ((ks * 64 + lg * 16) ^ ((row & 7) << 4)));
    }
    #pragma unroll
    for (int ni = 0; ni < 4; ++ni) {
      const int row = nw * 64 + ni * 16 + lr;
      bf_[ni] = *(const short8*)(smem + row * 256 + ((ks * 64 + lg * 16) ^ ((row & 7) << 4)));
    }
    #pragma unroll
    for (int mi = 0; mi < 4; ++mi)
      #pragma unroll
      for (int ni = 0; ni < 4; ++ni)
        acc[mi][ni] = __builtin_amdgcn_mfma_f32_16x16x32_bf16(af[mi], bf_[ni], acc[mi][ni], 0, 0, 0);
  }

  // epilogue: relu(acc+b2), mask k>=M to 0 (relu>=0, k=0 valid => exact), max over k
  const int cId = g0 + mw;
  const int Mc = s_M[mw];
  #pragma unroll
  for (int ni = 0; ni < 4; ++ni) {
    const float b2v = b2[nw * 64 + ni * 16 + lr];
    float cm = 0.f;
    #pragma unroll
    for (int mi = 0; mi < 4; ++mi)
      #pragma unroll
      for (int rr = 0; rr < 4; ++rr) {
        const int k = mi * 16 + lg * 4 + rr;   // C layout: col=lane&15, row=(lane>>4)*4+reg
        const float v = fmaxf(acc[mi][ni][rr] + b2v, 0.f);
        cm = fmaxf(cm, k < Mc ? v : 0.f);
      }
    cm = fmaxf(cm, __shfl_xor(cm, 16, 64));
    cm = fmaxf(cm, __shfl_xor(cm, 32, 64));
    if (ln < 16) out[(size_t)cId * HIDD + nw * 64 + ni * 16 + lr] = cm;
  }
}

// ============ pipelined heterogeneous kernel: launch c runs FPS[c] || bq[c-1] || mlp[c-2] ============
// 81KB LDS => exactly 1 block/CU: bq/mlp blocks can never co-reside with (and steal VALU
// from) the 16 FPS CUs on the critical path.
__global__ __launch_bounds__(256, 1) void pipe_kernel(int chunk,
                                                      const float* __restrict__ x,
                                                      const float* __restrict__ pos,
                                                      const float* __restrict__ W1,
                                                      const float* __restrict__ b1,
                                                      const float* __restrict__ W2,
                                                      const float* __restrict__ b2,
                                                      unsigned short* __restrict__ W2t,
                                                      int* __restrict__ fps_idx,
                                                      int* __restrict__ cnt,
                                                      int* __restrict__ nbr,
                                                      float* __restrict__ y1,
                                                      float* __restrict__ md_ws,
                                                      int* __restrict__ last_ws,
                                                      float* __restrict__ out,
                                                      float* __restrict__ pos_out,
                                                      float* __restrict__ batch_out) {
  __shared__ __align__(16) char smem[82944];
  const int bid = blockIdx.x;
  const int tid = threadIdx.x;

  if (chunk == 0) {
    if (bid < BB) {
      fps_role(0, bid, tid, pos, fps_idx, md_ws, last_ws, pos_out, batch_out, smem);
    } else if (bid < 16 + 8192) {
      y1_role(bid - 16, tid, x, W1, y1, smem);
    } else {
      for (int e = tid; e < HIDD * HIDD; e += 256) {
        const int n = e >> 7, hh = e & 127;
        W2t[e] = f2bf(W2[hh * HIDD + n]);   // W2t[n][h]
      }
    }
  } else if (chunk <= NCH - 1) {
    if (bid < BB) {
      fps_role(chunk, bid, tid, pos, fps_idx, md_ws, last_ws, pos_out, batch_out, smem);
    } else if (bid < 16 + 2048) {
      bq_role(chunk - 1, bid - 16, tid, pos, fps_idx, nbr, cnt, smem);
    } else {
      mlp_role(chunk - 2, bid - 2064, tid, pos, y1, W1, b1, W2t, b2, fps_idx, nbr, cnt, out, smem);
    }
  } else if (chunk == NCH) {
    if (bid < 2048) {
      bq_role(NCH - 1, bid, tid, pos, fps_idx, nbr, cnt, smem);
    } else {
      mlp_role(NCH - 2, bid - 2048, tid, pos, y1, W1, b1, W2t, b2, fps_idx, nbr, cnt, out, smem);
    }
  } else {
    mlp_role(NCH - 1, bid, tid, pos, y1, W1, b1, W2t, b2, fps_idx, nbr, cnt, out, smem);
  }
}

extern "C" void kernel_launch(void* const* d_in, const int* in_sizes, int n_in,
                              void* d_out, int out_size, void* d_ws, size_t ws_size,
                              hipStream_t stream) {
  const float* x   = (const float*)d_in[0];
  const float* pos = (const float*)d_in[1];
  const float* W1  = (const float*)d_in[3];
  const float* b1  = (const float*)d_in[4];
  const float* W2  = (const float*)d_in[5];
  const float* b2  = (const float*)d_in[6];

  float* out       = (float*)d_out;                   // [B*S, HID]
  float* pos_out   = out + (size_t)BB * SSS * HIDD;   // [B*S, 3]
  float* batch_out = pos_out + (size_t)BB * SSS * 3;  // [B*S]

  int* fps_idx        = (int*)d_ws;                                          // 64 KB
  int* cnt            = (int*)((char*)d_ws + 65536);                         // 64 KB
  unsigned short* W2t = (unsigned short*)((char*)d_ws + 131072);             // 32 KB
  int* last_ws        = (int*)((char*)d_ws + 163840);                        // 64 B
  int* nbr            = (int*)((char*)d_ws + 262144);                        // 4 MB
  float* y1           = (float*)((char*)d_ws + 262144 + 4194304);            // 32 MB
  float* md_ws        = (float*)((char*)d_ws + 262144 + 4194304 + 33554432); // 256 KB

  for (int c = 0; c <= NCH + 1; ++c) {
    int grid;
    if (c == 0) grid = 16 + 8192 + 1;
    else if (c == 1) grid = 16 + 2048;
    else if (c <= NCH - 1) grid = 16 + 2048 + 1024;
    else if (c == NCH) grid = 2048 + 1024;
    else grid = 1024;
    pipe_kernel<<<grid, 256, 0, stream>>>(c, x, pos, W1, b1, W2, b2, W2t,
                                          fps_idx, cnt, nbr, y1, md_ws, last_ws,
                                          out, pos_out, batch_out);
  }
}

// Round 9
// 1210.355 us; speedup vs baseline: 1.6586x; 1.6586x over previous
//
#include <hip/hip_runtime.h>
#include <cstdint>
#include <cstddef>

#define BB   16
#define NN   4096
#define CINN 64
#define KKK  64
#define HIDD 128
#define SSS  1024
#define MAXC 320
#define NCH  8
#define CHS  (SSS / NCH)   // 128 FPS steps per chunk

typedef __attribute__((ext_vector_type(8))) short short8;
typedef __attribute__((ext_vector_type(4))) float f32x4;
typedef unsigned long long u64;

// Exact f32 squared distance, numpy-style: ((dx*dx + dy*dy) + dz*dz), no FMA contraction.
// MUST stay bit-identical (absmax 0.0 in round 1 proved selection equivalence).
__device__ __forceinline__ float d2_exact(float ax, float ay, float az,
                                          float bx, float by, float bz) {
  float dx = __fsub_rn(ax, bx);
  float dy = __fsub_rn(ay, by);
  float dz = __fsub_rn(az, bz);
  return __fadd_rn(__fadd_rn(__fmul_rn(dx, dx), __fmul_rn(dy, dy)), __fmul_rn(dz, dz));
}

// f32 -> bf16 round-to-nearest-even (no NaN inputs here)
__device__ __forceinline__ unsigned short f2bf(float f) {
  unsigned u = __float_as_uint(f);
  return (unsigned short)((u + 0x7fffu + ((u >> 16) & 1u)) >> 16);
}

// ---------------- FPS role: chunked, 256 thr, 16 pts/thread, key-tree + u64-DPP argmax ----------------
__device__ __forceinline__ void fps_role(int chunk, int bid, int tid,
                                         const float* __restrict__ pos,
                                         int* __restrict__ fps_idx,
                                         float* __restrict__ md_ws,
                                         int* __restrict__ last_ws,
                                         float* __restrict__ pos_out,
                                         float* __restrict__ batch_out,
                                         char* smem) {
  float* px = (float*)smem;
  float* py = px + NN;
  float* pz = py + NN;
  u64* slots = (u64*)(pz + NN);  // [2][4] parity-double-buffered wave leaders
  const float* pb = pos + (size_t)bid * NN * 3;
  for (int i = tid; i < NN; i += 256) {
    px[i] = pb[3 * i + 0];
    py[i] = pb[3 * i + 1];
    pz[i] = pb[3 * i + 2];
  }
  if (chunk == 0) {
    #pragma unroll
    for (int kk = 0; kk < 4; ++kk)
      batch_out[bid * SSS + kk * 256 + tid] = (float)bid;
  }
  __syncthreads();

  float qx[16], qy[16], qz[16], md[16];
  #pragma unroll
  for (int j = 0; j < 16; ++j) {
    const int i = j * 256 + tid;
    qx[j] = px[i]; qy[j] = py[i]; qz[j] = pz[i];
    asm volatile("" : "+v"(qx[j]), "+v"(qy[j]), "+v"(qz[j]));
  }
  int last, tb;
  const int te = (chunk + 1) * CHS;
  if (chunk == 0) {
    #pragma unroll
    for (int j = 0; j < 16; ++j) md[j] = __builtin_inff();
    last = 0; tb = 1;
    if (tid == 0) {
      fps_idx[bid * SSS] = 0;
      pos_out[(size_t)bid * SSS * 3 + 0] = px[0];
      pos_out[(size_t)bid * SSS * 3 + 1] = py[0];
      pos_out[(size_t)bid * SSS * 3 + 2] = pz[0];
    }
  } else {
    #pragma unroll
    for (int j = 0; j < 16; ++j) md[j] = md_ws[bid * 4096 + j * 256 + tid];
    last = last_ws[bid]; tb = chunk * CHS;
  }

  for (int t = tb; t < te; ++t) {
    const float lx = px[last], ly = py[last], lz = pz[last];  // LDS broadcast
    // key_j = (md_j bits << 32) | ~idx : u64 max == (max val, lowest idx) == jnp.argmax.
    // Tree reduce (depth 4) replaces the 16-deep serial compare chain; keys are unique
    // (idx embedded) so semantics are identical.
    u64 kk[16];
    #pragma unroll
    for (int j = 0; j < 16; ++j) {
      const float d = d2_exact(qx[j], qy[j], qz[j], lx, ly, lz);
      md[j] = fminf(md[j], d);
      kk[j] = ((u64)__float_as_uint(md[j]) << 32) | (unsigned)(~(unsigned)(j * 256 + tid));
    }
    #pragma unroll
    for (int s = 8; s >= 1; s >>= 1)
      #pragma unroll
      for (int j = 0; j < s; ++j)
        if (kk[j + s] > kk[j]) kk[j] = kk[j + s];
    unsigned klo = (unsigned)(kk[0] & 0xffffffffull);
    unsigned khi = (unsigned)(kk[0] >> 32);
    // DPP wavefront max-reduce to lane 63 (round-7 proven).
#define FPS_DPP_STAGE(CTRL, RMASK)                                                            \
    {                                                                                          \
      unsigned slo = (unsigned)__builtin_amdgcn_update_dpp(0, (int)klo, CTRL, RMASK, 0xf, true); \
      unsigned shi = (unsigned)__builtin_amdgcn_update_dpp(0, (int)khi, CTRL, RMASK, 0xf, true); \
      if ((((u64)shi << 32) | slo) > (((u64)khi << 32) | klo)) { khi = shi; klo = slo; }       \
    }
    FPS_DPP_STAGE(0x111, 0xf)  // row_shr:1
    FPS_DPP_STAGE(0x112, 0xf)  // row_shr:2
    FPS_DPP_STAGE(0x114, 0xf)  // row_shr:4
    FPS_DPP_STAGE(0x118, 0xf)  // row_shr:8
    FPS_DPP_STAGE(0x142, 0xa)  // row_bcast:15
    FPS_DPP_STAGE(0x143, 0xc)  // row_bcast:31 -> lane63 = wave max
#undef FPS_DPP_STAGE
    u64* sl = slots + (t & 1) * 4;
    if ((tid & 63) == 63) sl[tid >> 6] = ((u64)khi << 32) | klo;
    __syncthreads();  // single barrier/step (parity buffers kill the WAR hazard)
    u64 mm = sl[0];
    #pragma unroll
    for (int w = 1; w < 4; ++w) mm = sl[w] > mm ? sl[w] : mm;
    last = (int)(~(unsigned)(mm & 0xffffffffull));
    if (tid == 0) {
      fps_idx[bid * SSS + t] = last;
      pos_out[((size_t)bid * SSS + t) * 3 + 0] = px[last];
      pos_out[((size_t)bid * SSS + t) * 3 + 1] = py[last];
      pos_out[((size_t)bid * SSS + t) * 3 + 2] = pz[last];
    }
  }
  if (chunk != NCH - 1) {
    #pragma unroll
    for (int j = 0; j < 16; ++j) md_ws[bid * 4096 + j * 256 + tid] = md[j];
    if (tid == 0) last_ws[bid] = last;
  }
}

// ---------------- y1 role: y1 = x @ W1[0:64,:], 8 points/block (round-3 proven) ----------------
__device__ __forceinline__ void y1_role(int i, int tid,
                                        const float* __restrict__ x,
                                        const float* __restrict__ W1,
                                        float* __restrict__ y1,
                                        char* smem) {
  float* sW = (float*)smem;             // [64][128] 32KB
  float* sx = (float*)(smem + 32768);   // [8][64] 2KB
  const int p0 = i * 8;
  for (int e = tid; e < CINN * HIDD; e += 256) sW[e] = W1[e];
  for (int e = tid; e < 8 * CINN; e += 256) sx[e] = x[(size_t)p0 * CINN + e];
  __syncthreads();
  const int h = tid & 127;
  const int pg = (tid >> 7) * 4;
  float a0 = 0.f, a1 = 0.f, a2 = 0.f, a3 = 0.f;
  for (int c = 0; c < CINN; ++c) {
    const float w = sW[c * HIDD + h];
    a0 = fmaf(sx[(pg + 0) * CINN + c], w, a0);
    a1 = fmaf(sx[(pg + 1) * CINN + c], w, a1);
    a2 = fmaf(sx[(pg + 2) * CINN + c], w, a2);
    a3 = fmaf(sx[(pg + 3) * CINN + c], w, a3);
  }
  y1[(size_t)(p0 + pg + 0) * HIDD + h] = a0;
  y1[(size_t)(p0 + pg + 1) * HIDD + h] = a1;
  y1[(size_t)(p0 + pg + 2) * HIDD + h] = a2;
  y1[(size_t)(p0 + pg + 3) * HIDD + h] = a3;
}

// ---------------- bq role: 8 centers/block, staged points (loads amortized 8x) ----------------
__device__ __forceinline__ void bq_role(int cc, int i, int tid,
                                        const float* __restrict__ pos,
                                        const int* __restrict__ fps_idx,
                                        int* __restrict__ nbr,
                                        int* __restrict__ cnt,
                                        char* smem) {
  const int b = i >> 4;                        // 16 blocks per cloud
  const int t0 = cc * CHS + (i & 15) * 8;      // 8 consecutive centers
  const int gbase = b * SSS + t0;
  float* px = (float*)smem;                    // SoA staged points, 48KB
  float* py = px + NN;
  float* pz = py + NN;
  float* cd = pz + NN;                         // [8][MAXC] d2
  int*   ci = (int*)(cd + 8 * MAXC);           // [8][MAXC] idx
  int*   ctr = ci + 8 * MAXC;                  // [8] append counters
  int*   scn = ctr + 8;                        // [8] sel counters
  float* cctr = (float*)(scn + 8);             // [8][3] center coords

  const float* pb = pos + (size_t)b * NN * 3;
  for (int p = tid; p < NN; p += 256) {
    px[p] = pb[3 * p + 0];
    py[p] = pb[3 * p + 1];
    pz[p] = pb[3 * p + 2];
  }
  if (tid < 8) { ctr[tid] = 0; scn[tid] = 0; }
  __syncthreads();
  if (tid < 8) {
    const int cp = fps_idx[gbase + tid];
    cctr[tid * 3 + 0] = px[cp];
    cctr[tid * 3 + 1] = py[cp];
    cctr[tid * 3 + 2] = pz[cp];
  }
  __syncthreads();
  float cx[8], cy[8], cz[8];
  #pragma unroll
  for (int c = 0; c < 8; ++c) {
    cx[c] = cctr[c * 3 + 0]; cy[c] = cctr[c * 3 + 1]; cz[c] = cctr[c * 3 + 2];
  }
  // scan: each staged point vs all 8 centers (same d2_exact => bit-identical selection)
  for (int s2 = 0; s2 < 16; ++s2) {
    const int p = s2 * 256 + tid;
    const float x = px[p], y = py[p], z = pz[p];
    #pragma unroll
    for (int c = 0; c < 8; ++c) {
      const float d2 = d2_exact(x, y, z, cx[c], cy[c], cz[c]);
      if (d2 <= 0.04f) {
        const int slot = atomicAdd(&ctr[c], 1);
        if (slot < MAXC) { cd[c * MAXC + slot] = d2; ci[c * MAXC + slot] = p; }
      }
    }
  }
  __syncthreads();
  // exact lex-rank (d2, idx) top-K == lax.top_k tie-break; order-independent
  #pragma unroll 1
  for (int c = 0; c < 8; ++c) {
    const int C = min(ctr[c], MAXC);
    for (int j = tid; j < C; j += 256) {
      const float dj = cd[c * MAXC + j];
      const int ij = ci[c * MAXC + j];
      int rank = 0;
      for (int m = 0; m < C; ++m) {
        const float dm = cd[c * MAXC + m];
        const int im = ci[c * MAXC + m];
        rank += (dm < dj || (dm == dj && im < ij)) ? 1 : 0;
      }
      if (rank < KKK) nbr[(size_t)(gbase + c) * KKK + atomicAdd(&scn[c], 1)] = ij;
    }
  }
  __syncthreads();
  if (tid < 8) cnt[gbase + tid] = scn[tid];
}

// ---------------- mlp role: gather + layer1-corr + bf16 MFMA layer2 + masked max ----------------
__device__ __forceinline__ void mlp_role(int cc, int i, int tid,
                                         const float* __restrict__ pos,
                                         const float* __restrict__ y1,
                                         const float* __restrict__ W1,
                                         const float* __restrict__ b1,
                                         const unsigned short* __restrict__ W2t,
                                         const float* __restrict__ b2,
                                         const int* __restrict__ fps_idx,
                                         const int* __restrict__ nbr,
                                         const int* __restrict__ cnt,
                                         float* __restrict__ out,
                                         char* smem) {
  const int b = i >> 6;
  const int g0 = b * SSS + cc * CHS + (i & 63) * 2;
  float* s_ctr = (float*)(smem + 65536);  // [2][3]
  int* s_M = (int*)(smem + 65568);        // [2]

  // stage W2t (128 rows x 256B, 16 uint4/row) with 16B XOR swizzle (T2)
  for (int c = tid; c < 2048; c += 256) {
    const int row = c >> 4;
    const int col = (c & 15) << 4;
    const uint4 v = ((const uint4*)W2t)[c];
    *(uint4*)(smem + row * 256 + (col ^ ((row & 7) << 4))) = v;
  }
  if (tid < 2) {
    s_M[tid] = min(cnt[g0 + tid], KKK);
    const int cp = fps_idx[g0 + tid];
    s_ctr[tid * 3 + 0] = pos[((size_t)b * NN + cp) * 3 + 0];
    s_ctr[tid * 3 + 1] = pos[((size_t)b * NN + cp) * 3 + 1];
    s_ctr[tid * 3 + 2] = pos[((size_t)b * NN + cp) * 3 + 2];
  }
  __syncthreads();

  const int wv = tid >> 6, ln = tid & 63;
  const float2 b1v = *(const float2*)(b1 + ln * 2);
  const float2 wav = *(const float2*)(W1 + 64 * HIDD + ln * 2);
  const float2 wbv = *(const float2*)(W1 + 65 * HIDD + ln * 2);
  const float2 wcv = *(const float2*)(W1 + 66 * HIDD + ln * 2);
  char* Hb = smem + 32768;
  for (int r = wv * 32; r < wv * 32 + 32; ++r) {   // row r: center r>>6, neighbor k=r&63
    const int ci = r >> 6, k = r & 63;
    unsigned val = 0u;
    if (k < s_M[ci]) {
      const int p = nbr[(size_t)(g0 + ci) * KKK + k];
      const float rx = pos[((size_t)b * NN + p) * 3 + 0] - s_ctr[ci * 3 + 0];
      const float ry = pos[((size_t)b * NN + p) * 3 + 1] - s_ctr[ci * 3 + 1];
      const float rz = pos[((size_t)b * NN + p) * 3 + 2] - s_ctr[ci * 3 + 2];
      const float2 yv = *(const float2*)(y1 + ((size_t)(b * NN + p)) * HIDD + ln * 2);
      float v0 = fmaxf(yv.x + b1v.x + rx * wav.x + ry * wbv.x + rz * wcv.x, 0.f);
      float v1 = fmaxf(yv.y + b1v.y + rx * wav.y + ry * wbv.y + rz * wcv.y, 0.f);
      val = (unsigned)f2bf(v0) | ((unsigned)f2bf(v1) << 16);
    }
    *(unsigned*)(Hb + r * 256 + ((ln * 4) ^ ((r & 7) << 4))) = val;
  }
  __syncthreads();

  // MFMA: wave (mw=center, nw=col-half); 4x4 16x16 tiles; K=128 in 4 steps of 32
  const int mw = wv >> 1, nw = wv & 1;
  const int lr = ln & 15, lg = ln >> 4;
  f32x4 zero = {0.f, 0.f, 0.f, 0.f};
  f32x4 acc[4][4];
  #pragma unroll
  for (int mi = 0; mi < 4; ++mi)
    #pragma unroll
    for (int ni = 0; ni < 4; ++ni) acc[mi][ni] = zero;

  #pragma unroll
  for (int ks = 0; ks < 4; ++ks) {
    short8 af[4], bf_[4];
    #pragma unroll
    for (int mi = 0; mi < 4; ++mi) {
      const int row = mw * 64 + mi * 16 + lr;
      af[mi] = *(const short8*)(Hb + row * 256 + ((ks * 64 + lg * 16) ^ ((row & 7) << 4)));
    }
    #pragma unroll
    for (int ni = 0; ni < 4; ++ni) {
      const int row = nw * 64 + ni * 16 + lr;
      bf_[ni] = *(const short8*)(smem + row * 256 + ((ks * 64 + lg * 16) ^ ((row & 7) << 4)));
    }
    #pragma unroll
    for (int mi = 0; mi < 4; ++mi)
      #pragma unroll
      for (int ni = 0; ni < 4; ++ni)
        acc[mi][ni] = __builtin_amdgcn_mfma_f32_16x16x32_bf16(af[mi], bf_[ni], acc[mi][ni], 0, 0, 0);
  }

  // epilogue: relu(acc+b2), mask k>=M to 0 (relu>=0, k=0 valid => exact), max over k
  const int cId = g0 + mw;
  const int Mc = s_M[mw];
  #pragma unroll
  for (int ni = 0; ni < 4; ++ni) {
    const float b2v = b2[nw * 64 + ni * 16 + lr];
    float cm = 0.f;
    #pragma unroll
    for (int mi = 0; mi < 4; ++mi)
      #pragma unroll
      for (int rr = 0; rr < 4; ++rr) {
        const int k = mi * 16 + lg * 4 + rr;   // C layout: col=lane&15, row=(lane>>4)*4+reg
        const float v = fmaxf(acc[mi][ni][rr] + b2v, 0.f);
        cm = fmaxf(cm, k < Mc ? v : 0.f);
      }
    cm = fmaxf(cm, __shfl_xor(cm, 16, 64));
    cm = fmaxf(cm, __shfl_xor(cm, 32, 64));
    if (ln < 16) out[(size_t)cId * HIDD + nw * 64 + ni * 16 + lr] = cm;
  }
}

// ============ pipelined heterogeneous kernel: launch c runs FPS[c] || bq[c-1] || mlp[c-2] ============
// LDS = 69824B => 2 blocks/CU (round-8 lesson: 82944B forced 1 block/CU and bq/mlp became
// the long pole at 244us/chunk).
__global__ __launch_bounds__(256) void pipe_kernel(int chunk,
                                                   const float* __restrict__ x,
                                                   const float* __restrict__ pos,
                                                   const float* __restrict__ W1,
                                                   const float* __restrict__ b1,
                                                   const float* __restrict__ W2,
                                                   const float* __restrict__ b2,
                                                   unsigned short* __restrict__ W2t,
                                                   int* __restrict__ fps_idx,
                                                   int* __restrict__ cnt,
                                                   int* __restrict__ nbr,
                                                   float* __restrict__ y1,
                                                   float* __restrict__ md_ws,
                                                   int* __restrict__ last_ws,
                                                   float* __restrict__ out,
                                                   float* __restrict__ pos_out,
                                                   float* __restrict__ batch_out) {
  __shared__ __align__(16) char smem[69824];
  const int bid = blockIdx.x;
  const int tid = threadIdx.x;

  if (chunk == 0) {
    if (bid < BB) {
      fps_role(0, bid, tid, pos, fps_idx, md_ws, last_ws, pos_out, batch_out, smem);
    } else if (bid < 16 + 8192) {
      y1_role(bid - 16, tid, x, W1, y1, smem);
    } else {
      for (int e = tid; e < HIDD * HIDD; e += 256) {
        const int n = e >> 7, hh = e & 127;
        W2t[e] = f2bf(W2[hh * HIDD + n]);   // W2t[n][h]
      }
    }
  } else if (chunk <= NCH - 1) {
    if (bid < BB) {
      fps_role(chunk, bid, tid, pos, fps_idx, md_ws, last_ws, pos_out, batch_out, smem);
    } else if (bid < 16 + 256) {
      bq_role(chunk - 1, bid - 16, tid, pos, fps_idx, nbr, cnt, smem);
    } else {
      mlp_role(chunk - 2, bid - 272, tid, pos, y1, W1, b1, W2t, b2, fps_idx, nbr, cnt, out, smem);
    }
  } else if (chunk == NCH) {
    if (bid < 256) {
      bq_role(NCH - 1, bid, tid, pos, fps_idx, nbr, cnt, smem);
    } else {
      mlp_role(NCH - 2, bid - 256, tid, pos, y1, W1, b1, W2t, b2, fps_idx, nbr, cnt, out, smem);
    }
  } else {
    mlp_role(NCH - 1, bid, tid, pos, y1, W1, b1, W2t, b2, fps_idx, nbr, cnt, out, smem);
  }
}

extern "C" void kernel_launch(void* const* d_in, const int* in_sizes, int n_in,
                              void* d_out, int out_size, void* d_ws, size_t ws_size,
                              hipStream_t stream) {
  const float* x   = (const float*)d_in[0];
  const float* pos = (const float*)d_in[1];
  const float* W1  = (const float*)d_in[3];
  const float* b1  = (const float*)d_in[4];
  const float* W2  = (const float*)d_in[5];
  const float* b2  = (const float*)d_in[6];

  float* out       = (float*)d_out;                   // [B*S, HID]
  float* pos_out   = out + (size_t)BB * SSS * HIDD;   // [B*S, 3]
  float* batch_out = pos_out + (size_t)BB * SSS * 3;  // [B*S]

  int* fps_idx        = (int*)d_ws;                                          // 64 KB
  int* cnt            = (int*)((char*)d_ws + 65536);                         // 64 KB
  unsigned short* W2t = (unsigned short*)((char*)d_ws + 131072);             // 32 KB
  int* last_ws        = (int*)((char*)d_ws + 163840);                        // 64 B
  int* nbr            = (int*)((char*)d_ws + 262144);                        // 4 MB
  float* y1           = (float*)((char*)d_ws + 262144 + 4194304);            // 32 MB
  float* md_ws        = (float*)((char*)d_ws + 262144 + 4194304 + 33554432); // 256 KB

  for (int c = 0; c <= NCH + 1; ++c) {
    int grid;
    if (c == 0) grid = 16 + 8192 + 1;
    else if (c == 1) grid = 16 + 256;
    else if (c <= NCH - 1) grid = 16 + 256 + 1024;
    else if (c == NCH) grid = 256 + 1024;
    else grid = 1024;
    pipe_kernel<<<grid, 256, 0, stream>>>(c, x, pos, W1, b1, W2, b2, W2t,
                                          fps_idx, cnt, nbr, y1, md_ws, last_ws,
                                          out, pos_out, batch_out);
  }
}